// Round 6
// baseline (1558.142 us; speedup 1.0000x reference)
//
#include <hip/hip_runtime.h>
#include <stdint.h>

#define S_LEN 2048
#define NH    16
#define DK    64
#define DM    1024

typedef __attribute__((ext_vector_type(8))) __bf16 bf16x8;
typedef __attribute__((ext_vector_type(4))) float  f32x4;

static __device__ __forceinline__ float bf2f(unsigned short u) {
    union { unsigned int u; float f; } v; v.u = ((unsigned int)u) << 16; return v.f;
}
static __device__ __forceinline__ unsigned short f2bf(float f) {
    union { float f; unsigned int u; } v; v.f = f;
    unsigned int r = v.u + 0x7FFFu + ((v.u >> 16) & 1u);
    return (unsigned short)(r >> 16);
}

// Load 8 contiguous elements as bf16x8 from bf16 (isf32=0) or fp32 (isf32=1).
static __device__ __forceinline__ bf16x8 ld8(const void* base, size_t eidx, int isf32) {
    if (isf32) {
        const float* p = (const float*)base + eidx;
        float4 a = *(const float4*)p;
        float4 b = *(const float4*)(p + 4);
        union { unsigned short u[8]; bf16x8 v; } r;
        r.u[0] = f2bf(a.x); r.u[1] = f2bf(a.y); r.u[2] = f2bf(a.z); r.u[3] = f2bf(a.w);
        r.u[4] = f2bf(b.x); r.u[5] = f2bf(b.y); r.u[6] = f2bf(b.z); r.u[7] = f2bf(b.w);
        return r.v;
    }
    return *(const bf16x8*)((const unsigned short*)base + eidx);
}

// ---------------------------------------------------------------------------
// Input dtype detector (fp32 low-halves have wild bf16 exponents).
// ---------------------------------------------------------------------------
__global__ void detect_f32(const unsigned short* __restrict__ x, int* __restrict__ flag)
{
    __shared__ int tot;
    if (threadIdx.x == 0) tot = 0;
    __syncthreads();
    int weird = 0;
    for (int i = threadIdx.x; i < 16384; i += 256) {
        int e = (x[i] >> 7) & 0xFF;
        if (e == 0 || e < 87 || e > 167) weird++;
    }
    atomicAdd(&tot, weird);
    __syncthreads();
    if (threadIdx.x == 0) *flag = (tot > 4000) ? 1 : 0;
}

#define LDSP 40   // padded K-stride for A/B staging (32 + 8)

// ---------------------------------------------------------------------------
// GEMM: C = A[M,K] * W[N,K]^T. A row-stride lda. Output: bf16 to C16 (ldc)
// if C16 != nullptr, else fp32 to C32 (ldc). m97-style MFMA core.
// ---------------------------------------------------------------------------
__global__ __launch_bounds__(256) void gemm_bt(const void* __restrict__ A, int lda,
                                               const void* __restrict__ W,
                                               unsigned short* __restrict__ C16,
                                               float* __restrict__ C32, int ldc,
                                               int K,
                                               const int* __restrict__ aflag,
                                               const int* __restrict__ wflag)
{
    __shared__ __align__(16) unsigned short As[128 * LDSP];
    __shared__ __align__(16) unsigned short Bs[128 * LDSP];
    const int a32 = aflag ? *aflag : 0;
    const int w32 = wflag ? *wflag : 0;
    const int tid  = threadIdx.x;
    const int wave = tid >> 6;
    const int lane = tid & 63;
    const int quad = lane >> 4;
    const int l16  = lane & 15;
    const int m0 = blockIdx.y * 128;
    const int n0 = blockIdx.x * 128;
    const int wm = (wave >> 1) * 64;
    const int wn = (wave & 1) * 64;

    const f32x4 vzero = {0.f, 0.f, 0.f, 0.f};
    f32x4 acc[4][4];
    for (int i = 0; i < 4; ++i)
        for (int j = 0; j < 4; ++j) acc[i][j] = vzero;

    for (int k0 = 0; k0 < K; k0 += 32) {
        __syncthreads();
        for (int c = tid; c < 512; c += 256) {
            int row = c >> 2;
            int col = (c & 3) << 3;
            *(bf16x8*)&As[row * LDSP + col] = ld8(A, (size_t)(m0 + row) * lda + k0 + col, a32);
            *(bf16x8*)&Bs[row * LDSP + col] = ld8(W, (size_t)(n0 + row) * K + k0 + col, w32);
        }
        __syncthreads();
        bf16x8 af[4], bfr[4];
        for (int mt = 0; mt < 4; ++mt)
            af[mt] = *(const bf16x8*)&As[(wm + mt * 16 + l16) * LDSP + quad * 8];
        for (int nt = 0; nt < 4; ++nt)
            bfr[nt] = *(const bf16x8*)&Bs[(wn + nt * 16 + l16) * LDSP + quad * 8];
        for (int mt = 0; mt < 4; ++mt)
            for (int nt = 0; nt < 4; ++nt)
                acc[mt][nt] = __builtin_amdgcn_mfma_f32_16x16x32_bf16(af[mt], bfr[nt], acc[mt][nt], 0, 0, 0);
    }

    for (int mt = 0; mt < 4; ++mt)
        for (int nt = 0; nt < 4; ++nt) {
            int col = n0 + wn + nt * 16 + l16;
            for (int r = 0; r < 4; ++r) {
                int row = m0 + wm + mt * 16 + quad * 4 + r;
                if (C16) C16[(size_t)row * ldc + col] = f2bf(acc[mt][nt][r]);
                else     C32[(size_t)row * ldc + col] = acc[mt][nt][r];
            }
        }
}

// ---------------------------------------------------------------------------
// In-place RoPE on qkv columns [0,2048). One thread per (token, h', pair);
// h' 0-15 = q heads (scaled 1/8), 16-31 = k heads.
// ---------------------------------------------------------------------------
__global__ __launch_bounds__(256) void rope_inplace(unsigned short* __restrict__ qkv)
{
    int tid = blockIdx.x * 256 + threadIdx.x;   // 8192*32*32 threads
    int p   = tid & 31;
    int hh  = (tid >> 5) & 31;
    int tok = tid >> 10;

    float invf = powf(10000.0f, -((float)p) * (1.0f / 32.0f));
    int s = tok & (S_LEN - 1);
    float sn, cs;
    sincosf((float)s * invf, &sn, &cs);
    float qs = (hh < NH) ? 0.125f : 1.0f;

    size_t e = (size_t)tok * 3072 + hh * 64 + 2 * p;
    float x1 = bf2f(qkv[e]), x2 = bf2f(qkv[e + 1]);
    qkv[e]     = f2bf((x1 * cs - x2 * sn) * qs);
    qkv[e + 1] = f2bf((x1 * sn + x2 * cs) * qs);
}

// ---------------------------------------------------------------------------
// V transpose: qkv cols [2048,3072) ([tok][h*64+d]) -> vt[b,h,d,s]
// ---------------------------------------------------------------------------
__global__ __launch_bounds__(256) void v_trans(const unsigned short* __restrict__ qkv,
                                               unsigned short* __restrict__ vt)
{
    __shared__ unsigned short tile[64][65];
    int blk = blockIdx.x;                 // B*NH*(S/64)
    int s0  = (blk & 31) * 64;
    int bh  = blk >> 5;
    int b   = bh >> 4;
    int h   = bh & 15;
    int t   = threadIdx.x;
    {
        int sl = t >> 2, dc = (t & 3) * 16;
        const unsigned short* src = qkv + (size_t)(b * S_LEN + s0 + sl) * 3072 + 2048 + h * DK + dc;
        for (int i = 0; i < 16; ++i) tile[sl][dc + i] = src[i];
    }
    __syncthreads();
    {
        int d = t >> 2, sc = (t & 3) * 16;
        unsigned short* dst = vt + ((size_t)bh * DK + d) * S_LEN + s0 + sc;
        for (int i = 0; i < 16; ++i) dst[i] = tile[sc + i][d];
    }
}

// ---------------------------------------------------------------------------
// Flash attention, causal, soft-cap 50*tanh(s/50). One wave = 16 q rows;
// block = 4 waves = 64 q rows of one (b,h). Uniform chunk count per block.
// q/k read strided from qkv (lda=3072); output into dead V columns.
// ---------------------------------------------------------------------------
#define PP 40
#define NEG_BIG (-30000.0f)

__global__ __launch_bounds__(256) void attn_fwd(unsigned short* __restrict__ qkv,
                                                const unsigned short* __restrict__ vt)
{
    __shared__ __align__(16) unsigned short plds[4][16 * PP];
    int blk  = blockIdx.x;                // B*NH*(S/64)
    int qblk = blk & 31;
    int bh   = blk >> 5;
    int b    = bh >> 4, h = bh & 15;
    int wave = threadIdx.x >> 6;
    int lane = threadIdx.x & 63;
    int quad = lane >> 4, l16 = lane & 15;
    int q0w  = qblk * 64 + wave * 16;

    const unsigned short* qbase = qkv + (size_t)(b * S_LEN + q0w) * 3072 + h * DK;
    const unsigned short* kbase = qkv + (size_t)b * S_LEN * 3072 + 1024 + h * DK;
    const unsigned short* vbase = vt + (size_t)bh * DK * S_LEN;

    bf16x8 qf0 = *(const bf16x8*)&qbase[(size_t)l16 * 3072 + quad * 8];
    bf16x8 qf1 = *(const bf16x8*)&qbase[(size_t)l16 * 3072 + 32 + quad * 8];

    const f32x4 vzero = {0.f, 0.f, 0.f, 0.f};
    float m_i[4], l_i[4];
    f32x4 o[4];
    for (int r = 0; r < 4; ++r) { m_i[r] = NEG_BIG; l_i[r] = 0.f; }
    for (int dt = 0; dt < 4; ++dt) o[dt] = vzero;

    unsigned short* pw = &plds[wave][0];
    int nch = qblk * 2 + 2;   // uniform across block: keys up to qblk*64+63

    for (int c = 0; c < nch; ++c) {
        int j0 = c * 32;
        f32x4 sc0 = vzero, sc1 = vzero;
        {
            const unsigned short* kp = &kbase[(size_t)(j0 + l16) * 3072 + quad * 8];
            bf16x8 k00 = *(const bf16x8*)kp;
            bf16x8 k01 = *(const bf16x8*)(kp + 32);
            sc0 = __builtin_amdgcn_mfma_f32_16x16x32_bf16(qf0, k00, sc0, 0, 0, 0);
            sc0 = __builtin_amdgcn_mfma_f32_16x16x32_bf16(qf1, k01, sc0, 0, 0, 0);
            const unsigned short* kp1 = kp + 16 * 3072;
            bf16x8 k10 = *(const bf16x8*)kp1;
            bf16x8 k11 = *(const bf16x8*)(kp1 + 32);
            sc1 = __builtin_amdgcn_mfma_f32_16x16x32_bf16(qf0, k10, sc1, 0, 0, 0);
            sc1 = __builtin_amdgcn_mfma_f32_16x16x32_bf16(qf1, k11, sc1, 0, 0, 0);
        }
        for (int r = 0; r < 4; ++r) {
            int qrow = q0w + quad * 4 + r;
            float v0 = 50.0f * tanhf(sc0[r] * 0.02f);
            float v1 = 50.0f * tanhf(sc1[r] * 0.02f);
            if (j0 + l16 > qrow)      v0 = NEG_BIG;
            if (j0 + 16 + l16 > qrow) v1 = NEG_BIG;
            float mx = fmaxf(v0, v1);
            for (int off = 1; off < 16; off <<= 1) mx = fmaxf(mx, __shfl_xor(mx, off));
            float mnew  = fmaxf(m_i[r], mx);
            float alpha = __expf(m_i[r] - mnew);
            float p0 = __expf(v0 - mnew);
            float p1 = __expf(v1 - mnew);
            float rs = p0 + p1;
            for (int off = 1; off < 16; off <<= 1) rs += __shfl_xor(rs, off);
            l_i[r] = l_i[r] * alpha + rs;
            m_i[r] = mnew;
            for (int dt = 0; dt < 4; ++dt) o[dt][r] *= alpha;
            pw[(quad * 4 + r) * PP + l16]      = f2bf(p0);
            pw[(quad * 4 + r) * PP + 16 + l16] = f2bf(p1);
        }
        __syncthreads();   // P write -> P read (uniform trip count)
        bf16x8 pf = *(const bf16x8*)&pw[l16 * PP + quad * 8];
        for (int dt = 0; dt < 4; ++dt) {
            bf16x8 vf = *(const bf16x8*)&vbase[(size_t)(dt * 16 + l16) * S_LEN + j0 + quad * 8];
            o[dt] = __builtin_amdgcn_mfma_f32_16x16x32_bf16(pf, vf, o[dt], 0, 0, 0);
        }
        __syncthreads();   // P read -> next P write
    }

    // write into dead V columns [2048,3072): aout[tok][h*64+d]
    for (int dt = 0; dt < 4; ++dt)
        for (int r = 0; r < 4; ++r) {
            int qrow = q0w + quad * 4 + r;
            qkv[(size_t)(b * S_LEN + qrow) * 3072 + 2048 + h * DK + dt * 16 + l16] = f2bf(o[dt][r] / l_i[r]);
        }
}

// ---------------------------------------------------------------------------
extern "C" void kernel_launch(void* const* d_in, const int* in_sizes, int n_in,
                              void* d_out, int out_size, void* d_ws, size_t ws_size,
                              hipStream_t stream)
{
    // identify inputs by element count (robust to ordering)
    const void* x = nullptr; const void* wqkv = nullptr; const void* wout = nullptr;
    for (int i = 0; i < n_in; ++i) {
        if      (in_sizes[i] == 8388608) x    = d_in[i];   // [4,2048,1024]
        else if (in_sizes[i] == 3145728) wqkv = d_in[i];   // [3072,1024]
        else if (in_sizes[i] == 1048576) wout = d_in[i];   // [1024,1024]
    }
    float* out = (float*)d_out;   // [4,2048,1024] FP32 (reference output dtype)
    unsigned short* ws  = (unsigned short*)d_ws;

    // ws: qkv [8192][3072] bf16 (48 MiB) + flag (4 B)
    unsigned short* qkv = ws;
    int* flag           = (int*)(ws + (size_t)8192 * 3072);
    // vt [b,h,d,s] bf16 (16.7 MB) stages in d_out (fp32 alloc = 33.5 MB);
    // fully consumed by attn_fwd before the final GEMM overwrites d_out.
    unsigned short* vt  = (unsigned short*)d_out;

    // 0) input dtype autodetect (bf16 expected; fp32 fallback)
    detect_f32<<<1, 256, 0, stream>>>((const unsigned short*)x, flag);
    // 1) qkv = x @ w_qkv^T  (M=8192, N=3072, K=1024), bf16 row-major
    gemm_bt<<<dim3(24, 64), 256, 0, stream>>>(x, 1024, wqkv, qkv, nullptr, 3072, 1024, flag, flag);
    // 2) in-place RoPE on q,k columns (q scaled 1/8)
    rope_inplace<<<32768, 256, 0, stream>>>(qkv);
    // 3) v columns -> vt[b,h,d,s]
    v_trans<<<2048, 256, 0, stream>>>(qkv, vt);
    // 4) causal soft-capped flash attention; output into dead V columns
    attn_fwd<<<2048, 256, 0, stream>>>(qkv, vt);
    // 5) out = aout @ w_out^T  (M=8192, N=1024, K=1024) -> FP32 d_out
    gemm_bt<<<dim3(8, 64), 256, 0, stream>>>(qkv + 2048, 3072, wout, nullptr, out, 1024, 1024, nullptr, flag);
}

// Round 7
// 1500.615 us; speedup vs baseline: 1.0383x; 1.0383x over previous
//
#include <hip/hip_runtime.h>
#include <stdint.h>

#define S_LEN 2048
#define NH    16
#define DK    64
#define DM    1024

typedef __attribute__((ext_vector_type(8))) __bf16 bf16x8;
typedef __attribute__((ext_vector_type(8))) unsigned short u16x8;
typedef __attribute__((ext_vector_type(4))) float  f32x4;

static __device__ __forceinline__ float bf2f(unsigned short u) {
    union { unsigned int u; float f; } v; v.u = ((unsigned int)u) << 16; return v.f;
}
static __device__ __forceinline__ unsigned short f2bf(float f) {
    union { float f; unsigned int u; } v; v.f = f;
    unsigned int r = v.u + 0x7FFFu + ((v.u >> 16) & 1u);
    return (unsigned short)(r >> 16);
}

// ---------------------------------------------------------------------------
// Input dtype detector (fp32 low-halves have wild bf16 exponents).
// ---------------------------------------------------------------------------
__global__ void detect_f32(const unsigned short* __restrict__ x, int* __restrict__ flag)
{
    __shared__ int tot;
    if (threadIdx.x == 0) tot = 0;
    __syncthreads();
    int weird = 0;
    for (int i = threadIdx.x; i < 16384; i += 256) {
        int e = (x[i] >> 7) & 0xFF;
        if (e == 0 || e < 87 || e > 167) weird++;
    }
    atomicAdd(&tot, weird);
    __syncthreads();
    if (threadIdx.x == 0) *flag = (tot > 4000) ? 1 : 0;
}

// ---------------------------------------------------------------------------
// Normalize an input buffer to bf16 (copy if already bf16, convert if fp32).
// Keeps runtime-dtype branches OUT of the GEMM hot loops (the round-6 spill).
// 8 elems/thread; n must be a multiple of 8.
// ---------------------------------------------------------------------------
__global__ __launch_bounds__(256) void norm_bf16(const void* __restrict__ src,
                                                 unsigned short* __restrict__ dst,
                                                 int n, const int* __restrict__ flag)
{
    const int isf32 = *flag;
    int i = (blockIdx.x * 256 + threadIdx.x) * 8;
    if (i >= n) return;
    if (isf32) {
        const float* p = (const float*)src + i;
        u16x8 o;
#pragma unroll
        for (int j = 0; j < 8; ++j) o[j] = f2bf(p[j]);
        *(u16x8*)&dst[i] = o;
    } else {
        *(uint4*)&dst[i] = *(const uint4*)((const unsigned short*)src + i);
    }
}

#define LDSP 40   // padded K-stride for A/B staging (32 + 8)
#define VST  136  // padded s-stride for V transpose staging (128 + 8)

// ---------------------------------------------------------------------------
// Fused QKV GEMM: qkv = x @ w_qkv^T (M=8192, N=3072, K=1024); epilogue fans
// out to qr/kr (rope'd, [b,h,s,d], q pre-scaled 1/8) and vt ([b,h,d,s]).
// Pure bf16 inputs — no dtype branches in the hot loop (round-6 spill fix).
// ---------------------------------------------------------------------------
__global__ __launch_bounds__(256) void gemm_fused(const unsigned short* __restrict__ A,
                                                  const unsigned short* __restrict__ W,
                                                  unsigned short* __restrict__ qr,
                                                  unsigned short* __restrict__ kr,
                                                  unsigned short* __restrict__ vt)
{
    __shared__ __align__(16) unsigned short smem[128 * VST]; // As/Bs union V-stage
    unsigned short* As = smem;
    unsigned short* Bs = smem + 128 * LDSP;

    const int tid  = threadIdx.x;
    const int wave = tid >> 6;
    const int lane = tid & 63;
    const int quad = lane >> 4;
    const int l16  = lane & 15;
    const int m0 = blockIdx.y * 128;
    const int n0 = blockIdx.x * 128;
    const int wm = (wave >> 1) * 64;
    const int wn = (wave & 1) * 64;
    const int K  = 1024;

    const f32x4 vzero = {0.f, 0.f, 0.f, 0.f};
    f32x4 acc[4][4];
    for (int i = 0; i < 4; ++i)
        for (int j = 0; j < 4; ++j) acc[i][j] = vzero;

    for (int k0 = 0; k0 < K; k0 += 32) {
        __syncthreads();
        for (int c = tid; c < 512; c += 256) {
            int row = c >> 2;
            int col = (c & 3) << 3;
            *(bf16x8*)&As[row * LDSP + col] = *(const bf16x8*)&A[(size_t)(m0 + row) * K + k0 + col];
            *(bf16x8*)&Bs[row * LDSP + col] = *(const bf16x8*)&W[(size_t)(n0 + row) * K + k0 + col];
        }
        __syncthreads();
        bf16x8 af[4], bfr[4];
        for (int mt = 0; mt < 4; ++mt)
            af[mt] = *(const bf16x8*)&As[(wm + mt * 16 + l16) * LDSP + quad * 8];
        for (int nt = 0; nt < 4; ++nt)
            bfr[nt] = *(const bf16x8*)&Bs[(wn + nt * 16 + l16) * LDSP + quad * 8];
        for (int mt = 0; mt < 4; ++mt)
            for (int nt = 0; nt < 4; ++nt)
                acc[mt][nt] = __builtin_amdgcn_mfma_f32_16x16x32_bf16(af[mt], bfr[nt], acc[mt][nt], 0, 0, 0);
    }

    const int cls = n0 >> 10;   // 0=Q, 1=K, 2=V  (block-uniform)
    if (cls < 2) {
        unsigned short* dst = cls ? kr : qr;
        const float qs = cls ? 1.0f : 0.125f;   // fold 1/sqrt(64) into q
        for (int nt = 0; nt < 4; ++nt) {
            int col = (n0 & 1023) + wn + nt * 16 + l16;   // 0..1023
            int h = col >> 6, d = col & 63;
            float invf = powf(10000.0f, -(float)(d >> 1) * (1.0f / 32.0f));
            int even = !(d & 1);
            for (int mt = 0; mt < 4; ++mt)
                for (int r = 0; r < 4; ++r) {
                    int row = m0 + wm + mt * 16 + quad * 4 + r;   // global token
                    int s = row & (S_LEN - 1), b = row >> 11;
                    float sn, cs;
                    sincosf((float)s * invf, &sn, &cs);
                    float own = acc[mt][nt][r];
                    float oth = __shfl_xor(own, 1);   // rope partner: adjacent lane
                    float res = even ? (own * cs - oth * sn) : (oth * sn + own * cs);
                    dst[((size_t)(b * NH + h) * S_LEN + s) * DK + d] = f2bf(res * qs);
                }
        }
    } else {
        __syncthreads();   // As/Bs done; reuse smem as vstage[d][s], stride VST
        for (int nt = 0; nt < 4; ++nt) {
            int dl = wn + nt * 16 + l16;
            for (int mt = 0; mt < 4; ++mt)
                for (int r = 0; r < 4; ++r)
                    smem[dl * VST + wm + mt * 16 + quad * 4 + r] = f2bf(acc[mt][nt][r]);
        }
        __syncthreads();
        int dl = tid >> 1, sh = (tid & 1) * 64;
        int vcol = (n0 - 2048) + dl;          // 0..1023
        int h = vcol >> 6, dd = vcol & 63;
        int b = m0 >> 11, s0 = m0 & (S_LEN - 1);
        unsigned short* dst = vt + (((size_t)(b * NH + h) * DK + dd) * S_LEN + s0 + sh);
        const unsigned short* src = smem + dl * VST + sh;
        for (int i = 0; i < 64; i += 8)
            *(bf16x8*)&dst[i] = *(const bf16x8*)&src[i];
    }
}

// ---------------------------------------------------------------------------
// Out projection GEMM: C_fp32 = A_bf16[M,K] @ W_bf16[N,K]^T. Pure, no branches.
// ---------------------------------------------------------------------------
__global__ __launch_bounds__(256) void gemm_out(const unsigned short* __restrict__ A,
                                                const unsigned short* __restrict__ W,
                                                float* __restrict__ C)
{
    __shared__ __align__(16) unsigned short As[128 * LDSP];
    __shared__ __align__(16) unsigned short Bs[128 * LDSP];
    const int tid  = threadIdx.x;
    const int wave = tid >> 6;
    const int lane = tid & 63;
    const int quad = lane >> 4;
    const int l16  = lane & 15;
    const int m0 = blockIdx.y * 128;
    const int n0 = blockIdx.x * 128;
    const int wm = (wave >> 1) * 64;
    const int wn = (wave & 1) * 64;
    const int K = 1024, ldc = 1024;

    const f32x4 vzero = {0.f, 0.f, 0.f, 0.f};
    f32x4 acc[4][4];
    for (int i = 0; i < 4; ++i)
        for (int j = 0; j < 4; ++j) acc[i][j] = vzero;

    for (int k0 = 0; k0 < K; k0 += 32) {
        __syncthreads();
        for (int c = tid; c < 512; c += 256) {
            int row = c >> 2;
            int col = (c & 3) << 3;
            *(bf16x8*)&As[row * LDSP + col] = *(const bf16x8*)&A[(size_t)(m0 + row) * K + k0 + col];
            *(bf16x8*)&Bs[row * LDSP + col] = *(const bf16x8*)&W[(size_t)(n0 + row) * K + k0 + col];
        }
        __syncthreads();
        bf16x8 af[4], bfr[4];
        for (int mt = 0; mt < 4; ++mt)
            af[mt] = *(const bf16x8*)&As[(wm + mt * 16 + l16) * LDSP + quad * 8];
        for (int nt = 0; nt < 4; ++nt)
            bfr[nt] = *(const bf16x8*)&Bs[(wn + nt * 16 + l16) * LDSP + quad * 8];
        for (int mt = 0; mt < 4; ++mt)
            for (int nt = 0; nt < 4; ++nt)
                acc[mt][nt] = __builtin_amdgcn_mfma_f32_16x16x32_bf16(af[mt], bfr[nt], acc[mt][nt], 0, 0, 0);
    }

    for (int mt = 0; mt < 4; ++mt)
        for (int nt = 0; nt < 4; ++nt) {
            int col = n0 + wn + nt * 16 + l16;
            for (int r = 0; r < 4; ++r) {
                int row = m0 + wm + mt * 16 + quad * 4 + r;
                C[(size_t)row * ldc + col] = acc[mt][nt][r];
            }
        }
}

// ---------------------------------------------------------------------------
// Flash attention, causal, soft-cap 50*tanh(s/50). One wave = 16 q rows;
// block = 4 waves = 64 q rows of one (b,h). Uniform chunk count per block.
// Packed qr/kr [b,h,s,d]; vt [b,h,d,s]; aout [tok][h*64+d].
// ---------------------------------------------------------------------------
#define PP 40
#define NEG_BIG (-30000.0f)

__global__ __launch_bounds__(256) void attn_fwd(const unsigned short* __restrict__ qr,
                                                const unsigned short* __restrict__ kr,
                                                const unsigned short* __restrict__ vt,
                                                unsigned short* __restrict__ aout)
{
    __shared__ __align__(16) unsigned short plds[4][16 * PP];
    int blk  = blockIdx.x;                // B*NH*(S/64)
    int qblk = blk & 31;
    int bh   = blk >> 5;
    int b    = bh >> 4, h = bh & 15;
    int wave = threadIdx.x >> 6;
    int lane = threadIdx.x & 63;
    int quad = lane >> 4, l16 = lane & 15;
    int q0w  = qblk * 64 + wave * 16;

    const unsigned short* qbase = qr + ((size_t)bh * S_LEN + q0w) * DK;
    const unsigned short* kbase = kr + (size_t)bh * S_LEN * DK;
    const unsigned short* vbase = vt + (size_t)bh * DK * S_LEN;

    bf16x8 qf0 = *(const bf16x8*)&qbase[l16 * DK + quad * 8];
    bf16x8 qf1 = *(const bf16x8*)&qbase[l16 * DK + 32 + quad * 8];

    const f32x4 vzero = {0.f, 0.f, 0.f, 0.f};
    float m_i[4], l_i[4];
    f32x4 o[4];
    for (int r = 0; r < 4; ++r) { m_i[r] = NEG_BIG; l_i[r] = 0.f; }
    for (int dt = 0; dt < 4; ++dt) o[dt] = vzero;

    unsigned short* pw = &plds[wave][0];
    int nch = qblk * 2 + 2;   // uniform across block: keys up to qblk*64+63

    for (int c = 0; c < nch; ++c) {
        int j0 = c * 32;
        f32x4 sc0 = vzero, sc1 = vzero;
        {
            const unsigned short* kp = &kbase[(size_t)(j0 + l16) * DK + quad * 8];
            bf16x8 k00 = *(const bf16x8*)kp;
            bf16x8 k01 = *(const bf16x8*)(kp + 32);
            sc0 = __builtin_amdgcn_mfma_f32_16x16x32_bf16(qf0, k00, sc0, 0, 0, 0);
            sc0 = __builtin_amdgcn_mfma_f32_16x16x32_bf16(qf1, k01, sc0, 0, 0, 0);
            const unsigned short* kp1 = kp + 16 * DK;
            bf16x8 k10 = *(const bf16x8*)kp1;
            bf16x8 k11 = *(const bf16x8*)(kp1 + 32);
            sc1 = __builtin_amdgcn_mfma_f32_16x16x32_bf16(qf0, k10, sc1, 0, 0, 0);
            sc1 = __builtin_amdgcn_mfma_f32_16x16x32_bf16(qf1, k11, sc1, 0, 0, 0);
        }
        for (int r = 0; r < 4; ++r) {
            int qrow = q0w + quad * 4 + r;
            float v0 = 50.0f * tanhf(sc0[r] * 0.02f);
            float v1 = 50.0f * tanhf(sc1[r] * 0.02f);
            if (j0 + l16 > qrow)      v0 = NEG_BIG;
            if (j0 + 16 + l16 > qrow) v1 = NEG_BIG;
            float mx = fmaxf(v0, v1);
            for (int off = 1; off < 16; off <<= 1) mx = fmaxf(mx, __shfl_xor(mx, off));
            float mnew  = fmaxf(m_i[r], mx);
            float alpha = __expf(m_i[r] - mnew);
            float p0 = __expf(v0 - mnew);
            float p1 = __expf(v1 - mnew);
            float rs = p0 + p1;
            for (int off = 1; off < 16; off <<= 1) rs += __shfl_xor(rs, off);
            l_i[r] = l_i[r] * alpha + rs;
            m_i[r] = mnew;
            for (int dt = 0; dt < 4; ++dt) o[dt][r] *= alpha;
            pw[(quad * 4 + r) * PP + l16]      = f2bf(p0);
            pw[(quad * 4 + r) * PP + 16 + l16] = f2bf(p1);
        }
        __syncthreads();   // P write -> P read (uniform trip count)
        bf16x8 pf = *(const bf16x8*)&pw[l16 * PP + quad * 8];
        for (int dt = 0; dt < 4; ++dt) {
            bf16x8 vf = *(const bf16x8*)&vbase[(size_t)(dt * 16 + l16) * S_LEN + j0 + quad * 8];
            o[dt] = __builtin_amdgcn_mfma_f32_16x16x32_bf16(pf, vf, o[dt], 0, 0, 0);
        }
        __syncthreads();   // P read -> next P write
    }

    for (int dt = 0; dt < 4; ++dt)
        for (int r = 0; r < 4; ++r) {
            int qrow = q0w + quad * 4 + r;
            aout[(size_t)(b * S_LEN + qrow) * DM + h * DK + dt * 16 + l16] = f2bf(o[dt][r] / l_i[r]);
        }
}

// ---------------------------------------------------------------------------
extern "C" void kernel_launch(void* const* d_in, const int* in_sizes, int n_in,
                              void* d_out, int out_size, void* d_ws, size_t ws_size,
                              hipStream_t stream)
{
    // identify inputs by element count (robust to ordering)
    const void* x = nullptr; const void* wqkv = nullptr; const void* wout = nullptr;
    for (int i = 0; i < n_in; ++i) {
        if      (in_sizes[i] == 8388608) x    = d_in[i];   // [4,2048,1024]
        else if (in_sizes[i] == 3145728) wqkv = d_in[i];   // [3072,1024]
        else if (in_sizes[i] == 1048576) wout = d_in[i];   // [1024,1024]
    }
    float* out = (float*)d_out;                      // [4,2048,1024] fp32
    unsigned short* ws   = (unsigned short*)d_ws;
    unsigned short* ob16 = (unsigned short*)d_out;   // d_out viewed as bf16 scratch

    // ws (48 MiB + 4 B): qr | kr | aout slots of 8,388,608 bf16 elems each.
    unsigned short* qr     = ws;
    unsigned short* kr     = ws + (size_t)8388608;
    unsigned short* aout   = ws + (size_t)16777216;
    int* flag              = (int*)(ws + (size_t)25165824);
    unsigned short* wqkvbf = aout;   // staged in aout slot; dead before attn writes
    unsigned short* woutbf = qr;     // staged in qr slot AFTER attn (qr then dead)

    // d_out bf16 view (16,777,216 elems): vt [0, 8.4M) | xbf [8.4M, 16.8M).
    // Both dead before gemm_out overwrites d_out with fp32 results.
    unsigned short* vt  = ob16;
    unsigned short* xbf = ob16 + (size_t)8388608;

    // 0) input dtype autodetect (bf16 expected; fp32 tolerated)
    detect_f32<<<1, 256, 0, stream>>>((const unsigned short*)x, flag);
    // 1) normalize x and w_qkv to bf16 (hot loops stay branch-free)
    norm_bf16<<<4096, 256, 0, stream>>>(x, xbf, 8388608, flag);
    norm_bf16<<<1536, 256, 0, stream>>>(wqkv, wqkvbf, 3145728, flag);
    // 2) fused: qkv GEMM + RoPE(q,k) -> qr/kr [b,h,s,d] (q/8), v -> vt [b,h,d,s]
    gemm_fused<<<dim3(24, 64), 256, 0, stream>>>(xbf, wqkvbf, qr, kr, vt);
    // 3) causal soft-capped flash attention -> aout [tok][1024]
    attn_fwd<<<2048, 256, 0, stream>>>(qr, kr, vt, aout);
    // 4) normalize w_out into the now-dead qr slot
    norm_bf16<<<512, 256, 0, stream>>>(wout, woutbf, 1048576, flag);
    // 5) out_fp32 = aout @ w_out^T  (M=8192, N=1024, K=1024)
    gemm_out<<<dim3(8, 64), 256, 0, stream>>>(aout, woutbf, out);
}

// Round 8
// 704.241 us; speedup vs baseline: 2.2125x; 2.1308x over previous
//
#include <hip/hip_runtime.h>
#include <stdint.h>

#define S_LEN 2048
#define NH    16
#define DK    64
#define DM    1024

typedef __attribute__((ext_vector_type(8))) __bf16 bf16x8;
typedef __attribute__((ext_vector_type(8))) unsigned short u16x8;
typedef __attribute__((ext_vector_type(4))) float  f32x4;

static __device__ __forceinline__ unsigned short f2bf(float f) {
    union { float f; unsigned int u; } v; v.f = f;
    unsigned int r = v.u + 0x7FFFu + ((v.u >> 16) & 1u);
    return (unsigned short)(r >> 16);
}

// ---------------------------------------------------------------------------
// Input dtype detector (fp32 low-halves have wild bf16 exponents).
// ---------------------------------------------------------------------------
__global__ void detect_f32(const unsigned short* __restrict__ x, int* __restrict__ flag)
{
    __shared__ int tot;
    if (threadIdx.x == 0) tot = 0;
    __syncthreads();
    int weird = 0;
    for (int i = threadIdx.x; i < 16384; i += 256) {
        int e = (x[i] >> 7) & 0xFF;
        if (e == 0 || e < 87 || e > 167) weird++;
    }
    atomicAdd(&tot, weird);
    __syncthreads();
    if (threadIdx.x == 0) *flag = (tot > 4000) ? 1 : 0;
}

// ---------------------------------------------------------------------------
// Normalize an input buffer to bf16 (copy if bf16, convert if fp32).
// ---------------------------------------------------------------------------
__global__ __launch_bounds__(256) void norm_bf16(const void* __restrict__ src,
                                                 unsigned short* __restrict__ dst,
                                                 int n, const int* __restrict__ flag)
{
    const int isf32 = *flag;
    int i = (blockIdx.x * 256 + threadIdx.x) * 8;
    if (i >= n) return;
    if (isf32) {
        const float* p = (const float*)src + i;
        u16x8 o;
        o[0] = f2bf(p[0]); o[1] = f2bf(p[1]); o[2] = f2bf(p[2]); o[3] = f2bf(p[3]);
        o[4] = f2bf(p[4]); o[5] = f2bf(p[5]); o[6] = f2bf(p[6]); o[7] = f2bf(p[7]);
        *(u16x8*)&dst[i] = o;
    } else {
        *(uint4*)&dst[i] = *(const uint4*)((const unsigned short*)src + i);
    }
}

#define LDSP 40   // padded K-stride for A/B staging (32 + 8)
#define VST  136  // padded s-stride for V transpose staging (128 + 8)

#define MFMA(a, b, c) __builtin_amdgcn_mfma_f32_16x16x32_bf16((a), (b), (c), 0, 0, 0)

// Shared GEMM mainloop: named accumulators (c00..c33) — NO local arrays, so
// nothing can be demoted to scratch (the round-6/7 3.2 GB spill).
#define GEMM_MAIN(Aptr, Wptr, lda_, ldw_)                                              \
    f32x4 zz = {0.f, 0.f, 0.f, 0.f};                                                   \
    f32x4 c00=zz,c01=zz,c02=zz,c03=zz, c10=zz,c11=zz,c12=zz,c13=zz,                    \
          c20=zz,c21=zz,c22=zz,c23=zz, c30=zz,c31=zz,c32=zz,c33=zz;                    \
    for (int k0 = 0; k0 < 1024; k0 += 32) {                                            \
        __syncthreads();                                                               \
        {                                                                              \
            int row = tid >> 2, col = (tid & 3) << 3;                                  \
            *(bf16x8*)&As[row * LDSP + col] =                                          \
                *(const bf16x8*)&Aptr[(size_t)(m0 + row) * (lda_) + k0 + col];         \
            *(bf16x8*)&Bs[row * LDSP + col] =                                          \
                *(const bf16x8*)&Wptr[(size_t)(n0 + row) * (ldw_) + k0 + col];         \
            row += 64;                                                                 \
            *(bf16x8*)&As[row * LDSP + col] =                                          \
                *(const bf16x8*)&Aptr[(size_t)(m0 + row) * (lda_) + k0 + col];         \
            *(bf16x8*)&Bs[row * LDSP + col] =                                          \
                *(const bf16x8*)&Wptr[(size_t)(n0 + row) * (ldw_) + k0 + col];         \
        }                                                                              \
        __syncthreads();                                                               \
        bf16x8 a0 = *(const bf16x8*)&As[(wm +  0 + l16) * LDSP + quad * 8];            \
        bf16x8 a1 = *(const bf16x8*)&As[(wm + 16 + l16) * LDSP + quad * 8];            \
        bf16x8 a2 = *(const bf16x8*)&As[(wm + 32 + l16) * LDSP + quad * 8];            \
        bf16x8 a3 = *(const bf16x8*)&As[(wm + 48 + l16) * LDSP + quad * 8];            \
        bf16x8 b0 = *(const bf16x8*)&Bs[(wn +  0 + l16) * LDSP + quad * 8];            \
        bf16x8 b1 = *(const bf16x8*)&Bs[(wn + 16 + l16) * LDSP + quad * 8];            \
        bf16x8 b2 = *(const bf16x8*)&Bs[(wn + 32 + l16) * LDSP + quad * 8];            \
        bf16x8 b3 = *(const bf16x8*)&Bs[(wn + 48 + l16) * LDSP + quad * 8];            \
        c00 = MFMA(a0, b0, c00); c01 = MFMA(a0, b1, c01);                              \
        c02 = MFMA(a0, b2, c02); c03 = MFMA(a0, b3, c03);                              \
        c10 = MFMA(a1, b0, c10); c11 = MFMA(a1, b1, c11);                              \
        c12 = MFMA(a1, b2, c12); c13 = MFMA(a1, b3, c13);                              \
        c20 = MFMA(a2, b0, c20); c21 = MFMA(a2, b1, c21);                              \
        c22 = MFMA(a2, b2, c22); c23 = MFMA(a2, b3, c23);                              \
        c30 = MFMA(a3, b0, c30); c31 = MFMA(a3, b1, c31);                              \
        c32 = MFMA(a3, b2, c32); c33 = MFMA(a3, b3, c33);                              \
    }

// ---------------------------------------------------------------------------
// Fused QKV GEMM + RoPE/V-transpose epilogue. All literal-index accesses.
// ---------------------------------------------------------------------------
__global__ __launch_bounds__(256) void gemm_fused(const unsigned short* __restrict__ A,
                                                  const unsigned short* __restrict__ W,
                                                  unsigned short* __restrict__ qr,
                                                  unsigned short* __restrict__ kr,
                                                  unsigned short* __restrict__ vt)
{
    __shared__ __align__(16) unsigned short smem[128 * VST]; // As/Bs union V-stage
    unsigned short* As = smem;
    unsigned short* Bs = smem + 128 * LDSP;

    const int tid  = threadIdx.x;
    const int wave = tid >> 6;
    const int lane = tid & 63;
    const int quad = lane >> 4;
    const int l16  = lane & 15;
    const int m0 = blockIdx.y * 128;
    const int n0 = blockIdx.x * 128;
    const int wm = (wave >> 1) * 64;
    const int wn = (wave & 1) * 64;

    GEMM_MAIN(A, W, 1024, 1024)

    const int cls = n0 >> 10;   // 0=Q, 1=K, 2=V  (block-uniform)
    if (cls < 2) {
        unsigned short* dst = cls ? kr : qr;
        const float qs = cls ? 1.0f : 0.125f;   // fold 1/sqrt(64) into q

#define ROPE_R(accv, MTc, rc, col_, h_, d_, invf_, even_) do {                         \
        int row = m0 + wm + (MTc) * 16 + quad * 4 + (rc);                              \
        int s = row & (S_LEN - 1), b = row >> 11;                                      \
        float sn, cs;                                                                  \
        sincosf((float)s * (invf_), &sn, &cs);                                         \
        float own = accv[rc];                                                          \
        float oth = __shfl_xor(own, 1);                                                \
        float res = (even_) ? (own * cs - oth * sn) : (oth * sn + own * cs);           \
        dst[((size_t)(b * NH + (h_)) * S_LEN + s) * DK + (d_)] = f2bf(res * qs);       \
    } while (0)

#define ROPE_ST(accv, MTc, NTc) do {                                                   \
        int col = (n0 & 1023) + wn + (NTc) * 16 + l16;                                 \
        int h = col >> 6, d = col & 63;                                                \
        float invf = exp2f(-(float)(d >> 1) * 0.41524101186f);                         \
        int even = !(d & 1);                                                           \
        ROPE_R(accv, MTc, 0, col, h, d, invf, even);                                   \
        ROPE_R(accv, MTc, 1, col, h, d, invf, even);                                   \
        ROPE_R(accv, MTc, 2, col, h, d, invf, even);                                   \
        ROPE_R(accv, MTc, 3, col, h, d, invf, even);                                   \
    } while (0)

        ROPE_ST(c00, 0, 0); ROPE_ST(c01, 0, 1); ROPE_ST(c02, 0, 2); ROPE_ST(c03, 0, 3);
        ROPE_ST(c10, 1, 0); ROPE_ST(c11, 1, 1); ROPE_ST(c12, 1, 2); ROPE_ST(c13, 1, 3);
        ROPE_ST(c20, 2, 0); ROPE_ST(c21, 2, 1); ROPE_ST(c22, 2, 2); ROPE_ST(c23, 2, 3);
        ROPE_ST(c30, 3, 0); ROPE_ST(c31, 3, 1); ROPE_ST(c32, 3, 2); ROPE_ST(c33, 3, 3);
    } else {
        __syncthreads();   // As/Bs done; reuse smem as vstage[d][s], stride VST

#define VST_ACC(accv, MTc, NTc) do {                                                   \
        int dl = wn + (NTc) * 16 + l16;                                                \
        int base = dl * VST + wm + (MTc) * 16 + quad * 4;                              \
        smem[base + 0] = f2bf(accv[0]); smem[base + 1] = f2bf(accv[1]);                \
        smem[base + 2] = f2bf(accv[2]); smem[base + 3] = f2bf(accv[3]);                \
    } while (0)

        VST_ACC(c00, 0, 0); VST_ACC(c01, 0, 1); VST_ACC(c02, 0, 2); VST_ACC(c03, 0, 3);
        VST_ACC(c10, 1, 0); VST_ACC(c11, 1, 1); VST_ACC(c12, 1, 2); VST_ACC(c13, 1, 3);
        VST_ACC(c20, 2, 0); VST_ACC(c21, 2, 1); VST_ACC(c22, 2, 2); VST_ACC(c23, 2, 3);
        VST_ACC(c30, 3, 0); VST_ACC(c31, 3, 1); VST_ACC(c32, 3, 2); VST_ACC(c33, 3, 3);
        __syncthreads();
        int dl = tid >> 1, sh = (tid & 1) * 64;
        int vcol = (n0 - 2048) + dl;          // 0..1023
        int h = vcol >> 6, dd = vcol & 63;
        int b = m0 >> 11, s0 = m0 & (S_LEN - 1);
        unsigned short* dst = vt + (((size_t)(b * NH + h) * DK + dd) * S_LEN + s0 + sh);
        const unsigned short* src = smem + dl * VST + sh;
#pragma unroll
        for (int i = 0; i < 64; i += 8)
            *(bf16x8*)&dst[i] = *(const bf16x8*)&src[i];
    }
}

// ---------------------------------------------------------------------------
// Out projection GEMM: C_fp32 = A_bf16 @ W_bf16^T.
// ---------------------------------------------------------------------------
__global__ __launch_bounds__(256) void gemm_out(const unsigned short* __restrict__ A,
                                                const unsigned short* __restrict__ W,
                                                float* __restrict__ C)
{
    __shared__ __align__(16) unsigned short As[128 * LDSP];
    __shared__ __align__(16) unsigned short Bs[128 * LDSP];
    const int tid  = threadIdx.x;
    const int wave = tid >> 6;
    const int lane = tid & 63;
    const int quad = lane >> 4;
    const int l16  = lane & 15;
    const int m0 = blockIdx.y * 128;
    const int n0 = blockIdx.x * 128;
    const int wm = (wave >> 1) * 64;
    const int wn = (wave & 1) * 64;

    GEMM_MAIN(A, W, 1024, 1024)

#define OUT_ST(accv, MTc, NTc) do {                                                    \
    int col = n0 + wn + (NTc) * 16 + l16;                                              \
    int rowb = m0 + wm + (MTc) * 16 + quad * 4;                                        \
    C[(size_t)(rowb + 0) * 1024 + col] = accv[0];                                      \
    C[(size_t)(rowb + 1) * 1024 + col] = accv[1];                                      \
    C[(size_t)(rowb + 2) * 1024 + col] = accv[2];                                      \
    C[(size_t)(rowb + 3) * 1024 + col] = accv[3];                                      \
} while (0)

    OUT_ST(c00, 0, 0); OUT_ST(c01, 0, 1); OUT_ST(c02, 0, 2); OUT_ST(c03, 0, 3);
    OUT_ST(c10, 1, 0); OUT_ST(c11, 1, 1); OUT_ST(c12, 1, 2); OUT_ST(c13, 1, 3);
    OUT_ST(c20, 2, 0); OUT_ST(c21, 2, 1); OUT_ST(c22, 2, 2); OUT_ST(c23, 2, 3);
    OUT_ST(c30, 3, 0); OUT_ST(c31, 3, 1); OUT_ST(c32, 3, 2); OUT_ST(c33, 3, 3);
}

// ---------------------------------------------------------------------------
// Flash attention, causal, soft-cap 50*tanh(s/50). One wave = 16 q rows;
// block = 4 waves = 64 q rows of one (b,h). Named state (no local arrays).
// ---------------------------------------------------------------------------
#define PP 40
#define NEG_BIG (-30000.0f)

__global__ __launch_bounds__(256) void attn_fwd(const unsigned short* __restrict__ qr,
                                                const unsigned short* __restrict__ kr,
                                                const unsigned short* __restrict__ vt,
                                                unsigned short* __restrict__ aout)
{
    __shared__ __align__(16) unsigned short plds[4][16 * PP];
    int blk  = blockIdx.x;                // B*NH*(S/64)
    int qblk = blk & 31;
    int bh   = blk >> 5;
    int b    = bh >> 4, h = bh & 15;
    int wave = threadIdx.x >> 6;
    int lane = threadIdx.x & 63;
    int quad = lane >> 4, l16 = lane & 15;
    int q0w  = qblk * 64 + wave * 16;

    const unsigned short* qbase = qr + ((size_t)bh * S_LEN + q0w) * DK;
    const unsigned short* kbase = kr + (size_t)bh * S_LEN * DK;
    const unsigned short* vbase = vt + (size_t)bh * DK * S_LEN;

    bf16x8 qf0 = *(const bf16x8*)&qbase[l16 * DK + quad * 8];
    bf16x8 qf1 = *(const bf16x8*)&qbase[l16 * DK + 32 + quad * 8];

    f32x4 zz = {0.f, 0.f, 0.f, 0.f};
    f32x4 o0 = zz, o1 = zz, o2 = zz, o3 = zz;
    float m0 = NEG_BIG, m1 = NEG_BIG, m2 = NEG_BIG, m3 = NEG_BIG;
    float l0 = 0.f, l1 = 0.f, l2 = 0.f, l3 = 0.f;

    unsigned short* pw = &plds[wave][0];
    int nch = qblk * 2 + 2;   // uniform across block: keys up to qblk*64+63

    for (int c = 0; c < nch; ++c) {
        int j0 = c * 32;
        f32x4 sc0 = zz, sc1 = zz;
        {
            const unsigned short* kp = &kbase[(size_t)(j0 + l16) * DK + quad * 8];
            bf16x8 k00 = *(const bf16x8*)kp;
            bf16x8 k01 = *(const bf16x8*)(kp + 32);
            sc0 = MFMA(qf0, k00, sc0);
            sc0 = MFMA(qf1, k01, sc0);
            const unsigned short* kp1 = kp + 16 * DK;
            bf16x8 k10 = *(const bf16x8*)kp1;
            bf16x8 k11 = *(const bf16x8*)(kp1 + 32);
            sc1 = MFMA(qf0, k10, sc1);
            sc1 = MFMA(qf1, k11, sc1);
        }

#define ROW_UPD(rc) do {                                                               \
        int qrow = q0w + quad * 4 + (rc);                                              \
        float v0 = 50.0f * tanhf(sc0[rc] * 0.02f);                                     \
        float v1 = 50.0f * tanhf(sc1[rc] * 0.02f);                                     \
        if (j0 + l16 > qrow)      v0 = NEG_BIG;                                        \
        if (j0 + 16 + l16 > qrow) v1 = NEG_BIG;                                        \
        float mx = fmaxf(v0, v1);                                                      \
        mx = fmaxf(mx, __shfl_xor(mx, 1)); mx = fmaxf(mx, __shfl_xor(mx, 2));          \
        mx = fmaxf(mx, __shfl_xor(mx, 4)); mx = fmaxf(mx, __shfl_xor(mx, 8));          \
        float mnew  = fmaxf(m##rc, mx);                                                \
        float alpha = __expf(m##rc - mnew);                                            \
        float p0 = __expf(v0 - mnew);                                                  \
        float p1 = __expf(v1 - mnew);                                                  \
        float rs = p0 + p1;                                                            \
        rs += __shfl_xor(rs, 1); rs += __shfl_xor(rs, 2);                              \
        rs += __shfl_xor(rs, 4); rs += __shfl_xor(rs, 8);                              \
        l##rc = l##rc * alpha + rs;                                                    \
        m##rc = mnew;                                                                  \
        o0[rc] *= alpha; o1[rc] *= alpha; o2[rc] *= alpha; o3[rc] *= alpha;            \
        pw[(quad * 4 + (rc)) * PP + l16]      = f2bf(p0);                              \
        pw[(quad * 4 + (rc)) * PP + 16 + l16] = f2bf(p1);                              \
    } while (0)

        ROW_UPD(0); ROW_UPD(1); ROW_UPD(2); ROW_UPD(3);

        __syncthreads();   // P write -> P read (uniform trip count)
        bf16x8 pf = *(const bf16x8*)&pw[l16 * PP + quad * 8];
        {
            const unsigned short* vp = &vbase[(size_t)l16 * S_LEN + j0 + quad * 8];
            bf16x8 vf0 = *(const bf16x8*)(vp);
            bf16x8 vf1 = *(const bf16x8*)(vp + 16 * S_LEN);
            bf16x8 vf2 = *(const bf16x8*)(vp + 32 * S_LEN);
            bf16x8 vf3 = *(const bf16x8*)(vp + 48 * S_LEN);
            o0 = MFMA(pf, vf0, o0);
            o1 = MFMA(pf, vf1, o1);
            o2 = MFMA(pf, vf2, o2);
            o3 = MFMA(pf, vf3, o3);
        }
        __syncthreads();   // P read -> next P write
    }

#define OUT_ROW(rc) do {                                                               \
    int qrow = q0w + quad * 4 + (rc);                                                  \
    size_t off = (size_t)(b * S_LEN + qrow) * DM + h * DK + l16;                       \
    float rl = 1.0f / l##rc;                                                           \
    aout[off +  0] = f2bf(o0[rc] * rl);                                                \
    aout[off + 16] = f2bf(o1[rc] * rl);                                                \
    aout[off + 32] = f2bf(o2[rc] * rl);                                                \
    aout[off + 48] = f2bf(o3[rc] * rl);                                                \
} while (0)

    OUT_ROW(0); OUT_ROW(1); OUT_ROW(2); OUT_ROW(3);
}

// ---------------------------------------------------------------------------
extern "C" void kernel_launch(void* const* d_in, const int* in_sizes, int n_in,
                              void* d_out, int out_size, void* d_ws, size_t ws_size,
                              hipStream_t stream)
{
    // identify inputs by element count (robust to ordering)
    const void* x = nullptr; const void* wqkv = nullptr; const void* wout = nullptr;
    for (int i = 0; i < n_in; ++i) {
        if      (in_sizes[i] == 8388608) x    = d_in[i];   // [4,2048,1024]
        else if (in_sizes[i] == 3145728) wqkv = d_in[i];   // [3072,1024]
        else if (in_sizes[i] == 1048576) wout = d_in[i];   // [1024,1024]
    }
    float* out = (float*)d_out;                      // [4,2048,1024] fp32
    unsigned short* ws   = (unsigned short*)d_ws;
    unsigned short* ob16 = (unsigned short*)d_out;   // d_out viewed as bf16 scratch

    // ws (48 MiB + 4 B): qr | kr | aout slots of 8,388,608 bf16 elems each.
    unsigned short* qr     = ws;
    unsigned short* kr     = ws + (size_t)8388608;
    unsigned short* aout   = ws + (size_t)16777216;
    int* flag              = (int*)(ws + (size_t)25165824);
    unsigned short* wqkvbf = aout;   // staged in aout slot; dead before attn writes
    unsigned short* woutbf = qr;     // staged in qr slot AFTER attn (qr then dead)

    // d_out bf16 view: vt [0, 8.4M) | xbf [8.4M, 16.8M); both dead before
    // gemm_out overwrites d_out with fp32 results.
    unsigned short* vt  = ob16;
    unsigned short* xbf = ob16 + (size_t)8388608;

    // 0) input dtype autodetect (bf16 expected; fp32 tolerated)
    detect_f32<<<1, 256, 0, stream>>>((const unsigned short*)x, flag);
    // 1) normalize x and w_qkv to bf16
    norm_bf16<<<4096, 256, 0, stream>>>(x, xbf, 8388608, flag);
    norm_bf16<<<1536, 256, 0, stream>>>(wqkv, wqkvbf, 3145728, flag);
    // 2) fused: qkv GEMM + RoPE(q,k) -> qr/kr [b,h,s,d] (q/8), v -> vt [b,h,d,s]
    gemm_fused<<<dim3(24, 64), 256, 0, stream>>>(xbf, wqkvbf, qr, kr, vt);
    // 3) causal soft-capped flash attention -> aout [tok][1024]
    attn_fwd<<<2048, 256, 0, stream>>>(qr, kr, vt, aout);
    // 4) normalize w_out into the now-dead qr slot
    norm_bf16<<<512, 256, 0, stream>>>(wout, woutbf, 1048576, flag);
    // 5) out_fp32 = aout @ w_out^T  (M=8192, N=1024, K=1024)
    gemm_out<<<dim3(8, 64), 256, 0, stream>>>(aout, woutbf, out);
}

// Round 9
// 699.859 us; speedup vs baseline: 2.2264x; 1.0063x over previous
//
#include <hip/hip_runtime.h>
#include <stdint.h>

#define S_LEN 2048
#define NH    16
#define DK    64
#define DM    1024

typedef __attribute__((ext_vector_type(8))) __bf16 bf16x8;
typedef __attribute__((ext_vector_type(8))) unsigned short u16x8;
typedef __attribute__((ext_vector_type(4))) float  f32x4;

static __device__ __forceinline__ unsigned short f2bf(float f) {
    union { float f; unsigned int u; } v; v.f = f;
    unsigned int r = v.u + 0x7FFFu + ((v.u >> 16) & 1u);
    return (unsigned short)(r >> 16);
}

// exp(50*tanh(s/50)) without libcalls: u=2^(2s/50/ln2)=e^(2s/50); tanh=1-2/(u+1)
static __device__ __forceinline__ float cap_exp(float s) {
    float u = exp2f(s * 0.0577078016f);              // e^(2s/50)
    float t = 1.0f - 2.0f * __builtin_amdgcn_rcpf(u + 1.0f);   // tanh(s/50)
    return exp2f(t * 72.1347520444f);                // e^(50*tanh)
}

// ---------------------------------------------------------------------------
// Input dtype detector (fp32 low-halves have wild bf16 exponents).
// ---------------------------------------------------------------------------
__global__ void detect_f32(const unsigned short* __restrict__ x, int* __restrict__ flag)
{
    __shared__ int tot;
    if (threadIdx.x == 0) tot = 0;
    __syncthreads();
    int weird = 0;
    for (int i = threadIdx.x; i < 16384; i += 256) {
        int e = (x[i] >> 7) & 0xFF;
        if (e == 0 || e < 87 || e > 167) weird++;
    }
    atomicAdd(&tot, weird);
    __syncthreads();
    if (threadIdx.x == 0) *flag = (tot > 4000) ? 1 : 0;
}

// ---------------------------------------------------------------------------
// Normalize an input buffer to bf16 (copy if bf16, convert if fp32).
// ---------------------------------------------------------------------------
__global__ __launch_bounds__(256) void norm_bf16(const void* __restrict__ src,
                                                 unsigned short* __restrict__ dst,
                                                 int n, const int* __restrict__ flag)
{
    const int isf32 = *flag;
    int i = (blockIdx.x * 256 + threadIdx.x) * 8;
    if (i >= n) return;
    if (isf32) {
        const float* p = (const float*)src + i;
        u16x8 o;
        o[0] = f2bf(p[0]); o[1] = f2bf(p[1]); o[2] = f2bf(p[2]); o[3] = f2bf(p[3]);
        o[4] = f2bf(p[4]); o[5] = f2bf(p[5]); o[6] = f2bf(p[6]); o[7] = f2bf(p[7]);
        *(u16x8*)&dst[i] = o;
    } else {
        *(uint4*)&dst[i] = *(const uint4*)((const unsigned short*)src + i);
    }
}

#define LDSP 40   // padded K-stride for A/B staging (32 + 8)
#define VST  136  // padded s-stride for V transpose staging (128 + 8)

#define MFMA(a, b, c) __builtin_amdgcn_mfma_f32_16x16x32_bf16((a), (b), (c), 0, 0, 0)

// Shared GEMM mainloop: named accumulators — no local arrays (scratch-spill fix).
#define GEMM_MAIN(Aptr, Wptr, lda_, ldw_)                                              \
    f32x4 zz = {0.f, 0.f, 0.f, 0.f};                                                   \
    f32x4 c00=zz,c01=zz,c02=zz,c03=zz, c10=zz,c11=zz,c12=zz,c13=zz,                    \
          c20=zz,c21=zz,c22=zz,c23=zz, c30=zz,c31=zz,c32=zz,c33=zz;                    \
    for (int k0 = 0; k0 < 1024; k0 += 32) {                                            \
        __syncthreads();                                                               \
        {                                                                              \
            int row = tid >> 2, col = (tid & 3) << 3;                                  \
            *(bf16x8*)&As[row * LDSP + col] =                                          \
                *(const bf16x8*)&Aptr[(size_t)(m0 + row) * (lda_) + k0 + col];         \
            *(bf16x8*)&Bs[row * LDSP + col] =                                          \
                *(const bf16x8*)&Wptr[(size_t)(n0 + row) * (ldw_) + k0 + col];         \
            row += 64;                                                                 \
            *(bf16x8*)&As[row * LDSP + col] =                                          \
                *(const bf16x8*)&Aptr[(size_t)(m0 + row) * (lda_) + k0 + col];         \
            *(bf16x8*)&Bs[row * LDSP + col] =                                          \
                *(const bf16x8*)&Wptr[(size_t)(n0 + row) * (ldw_) + k0 + col];         \
        }                                                                              \
        __syncthreads();                                                               \
        bf16x8 a0 = *(const bf16x8*)&As[(wm +  0 + l16) * LDSP + quad * 8];            \
        bf16x8 a1 = *(const bf16x8*)&As[(wm + 16 + l16) * LDSP + quad * 8];            \
        bf16x8 a2 = *(const bf16x8*)&As[(wm + 32 + l16) * LDSP + quad * 8];            \
        bf16x8 a3 = *(const bf16x8*)&As[(wm + 48 + l16) * LDSP + quad * 8];            \
        bf16x8 b0 = *(const bf16x8*)&Bs[(wn +  0 + l16) * LDSP + quad * 8];            \
        bf16x8 b1 = *(const bf16x8*)&Bs[(wn + 16 + l16) * LDSP + quad * 8];            \
        bf16x8 b2 = *(const bf16x8*)&Bs[(wn + 32 + l16) * LDSP + quad * 8];            \
        bf16x8 b3 = *(const bf16x8*)&Bs[(wn + 48 + l16) * LDSP + quad * 8];            \
        c00 = MFMA(a0, b0, c00); c01 = MFMA(a0, b1, c01);                              \
        c02 = MFMA(a0, b2, c02); c03 = MFMA(a0, b3, c03);                              \
        c10 = MFMA(a1, b0, c10); c11 = MFMA(a1, b1, c11);                              \
        c12 = MFMA(a1, b2, c12); c13 = MFMA(a1, b3, c13);                              \
        c20 = MFMA(a2, b0, c20); c21 = MFMA(a2, b1, c21);                              \
        c22 = MFMA(a2, b2, c22); c23 = MFMA(a2, b3, c23);                              \
        c30 = MFMA(a3, b0, c30); c31 = MFMA(a3, b1, c31);                              \
        c32 = MFMA(a3, b2, c32); c33 = MFMA(a3, b3, c33);                              \
    }

// ---------------------------------------------------------------------------
// Fused QKV GEMM + RoPE/V-transpose epilogue.
// ---------------------------------------------------------------------------
__global__ __launch_bounds__(256) void gemm_fused(const unsigned short* __restrict__ A,
                                                  const unsigned short* __restrict__ W,
                                                  unsigned short* __restrict__ qr,
                                                  unsigned short* __restrict__ kr,
                                                  unsigned short* __restrict__ vt)
{
    __shared__ __align__(16) unsigned short smem[128 * VST]; // As/Bs union V-stage
    unsigned short* As = smem;
    unsigned short* Bs = smem + 128 * LDSP;

    const int tid  = threadIdx.x;
    const int wave = tid >> 6;
    const int lane = tid & 63;
    const int quad = lane >> 4;
    const int l16  = lane & 15;
    const int m0 = blockIdx.y * 128;
    const int n0 = blockIdx.x * 128;
    const int wm = (wave >> 1) * 64;
    const int wn = (wave & 1) * 64;

    GEMM_MAIN(A, W, 1024, 1024)

    const int cls = n0 >> 10;   // 0=Q, 1=K, 2=V  (block-uniform)
    if (cls < 2) {
        unsigned short* dst = cls ? kr : qr;
        const float qs = cls ? 1.0f : 0.125f;   // fold 1/sqrt(64) into q

#define ROPE_R(accv, MTc, rc, invf_, even_, h_, d_) do {                               \
        int row = m0 + wm + (MTc) * 16 + quad * 4 + (rc);                              \
        int s = row & (S_LEN - 1), b = row >> 11;                                      \
        float sn, cs;                                                                  \
        sincosf((float)s * (invf_), &sn, &cs);                                         \
        float own = accv[rc];                                                          \
        float oth = __shfl_xor(own, 1);                                                \
        float res = (even_) ? (own * cs - oth * sn) : (oth * sn + own * cs);           \
        dst[((size_t)(b * NH + (h_)) * S_LEN + s) * DK + (d_)] = f2bf(res * qs);       \
    } while (0)

#define ROPE_ST(accv, MTc, NTc) do {                                                   \
        int col = (n0 & 1023) + wn + (NTc) * 16 + l16;                                 \
        int h = col >> 6, d = col & 63;                                                \
        float invf = exp2f(-(float)(d >> 1) * 0.41524101186f);                         \
        int even = !(d & 1);                                                           \
        ROPE_R(accv, MTc, 0, invf, even, h, d);                                        \
        ROPE_R(accv, MTc, 1, invf, even, h, d);                                        \
        ROPE_R(accv, MTc, 2, invf, even, h, d);                                        \
        ROPE_R(accv, MTc, 3, invf, even, h, d);                                        \
    } while (0)

        ROPE_ST(c00, 0, 0); ROPE_ST(c01, 0, 1); ROPE_ST(c02, 0, 2); ROPE_ST(c03, 0, 3);
        ROPE_ST(c10, 1, 0); ROPE_ST(c11, 1, 1); ROPE_ST(c12, 1, 2); ROPE_ST(c13, 1, 3);
        ROPE_ST(c20, 2, 0); ROPE_ST(c21, 2, 1); ROPE_ST(c22, 2, 2); ROPE_ST(c23, 2, 3);
        ROPE_ST(c30, 3, 0); ROPE_ST(c31, 3, 1); ROPE_ST(c32, 3, 2); ROPE_ST(c33, 3, 3);
    } else {
        __syncthreads();   // As/Bs done; reuse smem as vstage[d][s], stride VST

#define VST_ACC(accv, MTc, NTc) do {                                                   \
        int dl = wn + (NTc) * 16 + l16;                                                \
        int base = dl * VST + wm + (MTc) * 16 + quad * 4;                              \
        smem[base + 0] = f2bf(accv[0]); smem[base + 1] = f2bf(accv[1]);                \
        smem[base + 2] = f2bf(accv[2]); smem[base + 3] = f2bf(accv[3]);                \
    } while (0)

        VST_ACC(c00, 0, 0); VST_ACC(c01, 0, 1); VST_ACC(c02, 0, 2); VST_ACC(c03, 0, 3);
        VST_ACC(c10, 1, 0); VST_ACC(c11, 1, 1); VST_ACC(c12, 1, 2); VST_ACC(c13, 1, 3);
        VST_ACC(c20, 2, 0); VST_ACC(c21, 2, 1); VST_ACC(c22, 2, 2); VST_ACC(c23, 2, 3);
        VST_ACC(c30, 3, 0); VST_ACC(c31, 3, 1); VST_ACC(c32, 3, 2); VST_ACC(c33, 3, 3);
        __syncthreads();
        int dl = tid >> 1, sh = (tid & 1) * 64;
        int vcol = (n0 - 2048) + dl;          // 0..1023
        int h = vcol >> 6, dd = vcol & 63;
        int b = m0 >> 11, s0 = m0 & (S_LEN - 1);
        unsigned short* dst = vt + (((size_t)(b * NH + h) * DK + dd) * S_LEN + s0 + sh);
        const unsigned short* src = smem + dl * VST + sh;
#pragma unroll
        for (int i = 0; i < 64; i += 8)
            *(bf16x8*)&dst[i] = *(const bf16x8*)&src[i];
    }
}

// ---------------------------------------------------------------------------
// Out projection GEMM: C_fp32 = A_bf16 @ W_bf16^T.
// ---------------------------------------------------------------------------
__global__ __launch_bounds__(256) void gemm_out(const unsigned short* __restrict__ A,
                                                const unsigned short* __restrict__ W,
                                                float* __restrict__ C)
{
    __shared__ __align__(16) unsigned short As[128 * LDSP];
    __shared__ __align__(16) unsigned short Bs[128 * LDSP];
    const int tid  = threadIdx.x;
    const int wave = tid >> 6;
    const int lane = tid & 63;
    const int quad = lane >> 4;
    const int l16  = lane & 15;
    const int m0 = blockIdx.y * 128;
    const int n0 = blockIdx.x * 128;
    const int wm = (wave >> 1) * 64;
    const int wn = (wave & 1) * 64;

    GEMM_MAIN(A, W, 1024, 1024)

#define OUT_ST(accv, MTc, NTc) do {                                                    \
    int col = n0 + wn + (NTc) * 16 + l16;                                              \
    int rowb = m0 + wm + (MTc) * 16 + quad * 4;                                        \
    C[(size_t)(rowb + 0) * 1024 + col] = accv[0];                                      \
    C[(size_t)(rowb + 1) * 1024 + col] = accv[1];                                      \
    C[(size_t)(rowb + 2) * 1024 + col] = accv[2];                                      \
    C[(size_t)(rowb + 3) * 1024 + col] = accv[3];                                      \
} while (0)

    OUT_ST(c00, 0, 0); OUT_ST(c01, 0, 1); OUT_ST(c02, 0, 2); OUT_ST(c03, 0, 3);
    OUT_ST(c10, 1, 0); OUT_ST(c11, 1, 1); OUT_ST(c12, 1, 2); OUT_ST(c13, 1, 3);
    OUT_ST(c20, 2, 0); OUT_ST(c21, 2, 1); OUT_ST(c22, 2, 2); OUT_ST(c23, 2, 3);
    OUT_ST(c30, 3, 0); OUT_ST(c31, 3, 1); OUT_ST(c32, 3, 2); OUT_ST(c33, 3, 3);
}

// ---------------------------------------------------------------------------
// Flash attention, causal, soft-cap 50*tanh(s/50).
// KEY INSIGHT: the soft-cap bounds scores to (-50,50), so p=exp(v) never
// overflows fp32/bf16 (p<=5.2e21, l<=1.1e25) -> NO online max, NO rescale,
// NO in-loop shuffle reductions. One wave = 16 q rows; 64-key chunks;
// per-wave P buffer in LDS (no __syncthreads — s_waitcnt lgkmcnt orders
// the intra-wave write->read, validated in round 3).
// ---------------------------------------------------------------------------
#define PPL 72   // P-row stride in LDS (64 keys + 8 pad)

__global__ __launch_bounds__(256) void attn_fwd(const unsigned short* __restrict__ qr,
                                                const unsigned short* __restrict__ kr,
                                                const unsigned short* __restrict__ vt,
                                                unsigned short* __restrict__ aout)
{
    __shared__ __align__(16) unsigned short plds[4][16 * PPL];
    int blk  = blockIdx.x;                // B*NH*(S/64)
    int qblk = blk & 31;
    int bh   = blk >> 5;
    int b    = bh >> 4, h = bh & 15;
    int wave = threadIdx.x >> 6;
    int lane = threadIdx.x & 63;
    int quad = lane >> 4, l16 = lane & 15;
    int q0w  = qblk * 64 + wave * 16;

    const unsigned short* qbase = qr + ((size_t)bh * S_LEN + q0w) * DK;
    const unsigned short* kbase = kr + (size_t)bh * S_LEN * DK;
    const unsigned short* vbase = vt + (size_t)bh * DK * S_LEN;

    bf16x8 qf0 = *(const bf16x8*)&qbase[l16 * DK + quad * 8];
    bf16x8 qf1 = *(const bf16x8*)&qbase[l16 * DK + 32 + quad * 8];

    f32x4 zz = {0.f, 0.f, 0.f, 0.f};
    f32x4 o0 = zz, o1 = zz, o2 = zz, o3 = zz;
    float l0 = 0.f, l1 = 0.f, l2 = 0.f, l3 = 0.f;

    unsigned short* pw = &plds[wave][0];
    const int nch = qblk + 1;   // 64-key chunks; all waves in block identical

    for (int c = 0; c < nch; ++c) {
        int j0 = c * 64;

        // ---- QK^T: 4 score tiles (16 keys each), K=64 via 2 MFMA ----
        const unsigned short* kp = &kbase[(size_t)(j0 + l16) * DK + quad * 8];
        f32x4 sc0 = zz, sc1 = zz, sc2 = zz, sc3 = zz;
        {
            bf16x8 ka = *(const bf16x8*)kp;
            bf16x8 kb = *(const bf16x8*)(kp + 32);
            sc0 = MFMA(qf0, ka, sc0); sc0 = MFMA(qf1, kb, sc0);
            ka = *(const bf16x8*)(kp + 16 * DK); kb = *(const bf16x8*)(kp + 16 * DK + 32);
            sc1 = MFMA(qf0, ka, sc1); sc1 = MFMA(qf1, kb, sc1);
            ka = *(const bf16x8*)(kp + 32 * DK); kb = *(const bf16x8*)(kp + 32 * DK + 32);
            sc2 = MFMA(qf0, ka, sc2); sc2 = MFMA(qf1, kb, sc2);
            ka = *(const bf16x8*)(kp + 48 * DK); kb = *(const bf16x8*)(kp + 48 * DK + 32);
            sc3 = MFMA(qf0, ka, sc3); sc3 = MFMA(qf1, kb, sc3);
        }

        // ---- V loads hoisted: overlap vmcnt with the softmax VALU below ----
        const unsigned short* vp = &vbase[(size_t)l16 * S_LEN + j0 + quad * 8];
        bf16x8 v00 = *(const bf16x8*)(vp);
        bf16x8 v01 = *(const bf16x8*)(vp + 32);
        bf16x8 v10 = *(const bf16x8*)(vp + 16 * S_LEN);
        bf16x8 v11 = *(const bf16x8*)(vp + 16 * S_LEN + 32);
        bf16x8 v20 = *(const bf16x8*)(vp + 32 * S_LEN);
        bf16x8 v21 = *(const bf16x8*)(vp + 32 * S_LEN + 32);
        bf16x8 v30 = *(const bf16x8*)(vp + 48 * S_LEN);
        bf16x8 v31 = *(const bf16x8*)(vp + 48 * S_LEN + 32);

        // ---- soft-cap exp + causal mask; lane-local l accumulation ----
#define ROW_UPD(rc) do {                                                               \
        int qrow = q0w + quad * 4 + (rc);                                              \
        float p0 = (j0 + l16      > qrow) ? 0.f : cap_exp(sc0[rc]);                    \
        float p1 = (j0 + 16 + l16 > qrow) ? 0.f : cap_exp(sc1[rc]);                    \
        float p2 = (j0 + 32 + l16 > qrow) ? 0.f : cap_exp(sc2[rc]);                    \
        float p3 = (j0 + 48 + l16 > qrow) ? 0.f : cap_exp(sc3[rc]);                    \
        l##rc += (p0 + p1) + (p2 + p3);                                                \
        int rb = (quad * 4 + (rc)) * PPL + l16;                                        \
        pw[rb]      = f2bf(p0);                                                        \
        pw[rb + 16] = f2bf(p1);                                                        \
        pw[rb + 32] = f2bf(p2);                                                        \
        pw[rb + 48] = f2bf(p3);                                                        \
    } while (0)

        ROW_UPD(0); ROW_UPD(1); ROW_UPD(2); ROW_UPD(3);

        // intra-wave LDS write->read ordering (per-wave buffer; no barrier)
        asm volatile("s_waitcnt lgkmcnt(0)" ::: "memory");

        // ---- PV: P (A-layout from LDS) x V tiles ----
        bf16x8 pf0 = *(const bf16x8*)&pw[l16 * PPL + quad * 8];
        bf16x8 pf1 = *(const bf16x8*)&pw[l16 * PPL + 32 + quad * 8];
        o0 = MFMA(pf0, v00, o0); o0 = MFMA(pf1, v01, o0);
        o1 = MFMA(pf0, v10, o1); o1 = MFMA(pf1, v11, o1);
        o2 = MFMA(pf0, v20, o2); o2 = MFMA(pf1, v21, o2);
        o3 = MFMA(pf0, v30, o3); o3 = MFMA(pf1, v31, o3);
    }

    // ---- deferred l reduction (16 lanes within quad) + output ----
#define OUT_ROW(rc) do {                                                               \
    float lr = l##rc;                                                                  \
    lr += __shfl_xor(lr, 1); lr += __shfl_xor(lr, 2);                                  \
    lr += __shfl_xor(lr, 4); lr += __shfl_xor(lr, 8);                                  \
    int qrow = q0w + quad * 4 + (rc);                                                  \
    size_t off = (size_t)(b * S_LEN + qrow) * DM + h * DK + l16;                       \
    float rl = 1.0f / lr;                                                              \
    aout[off +  0] = f2bf(o0[rc] * rl);                                                \
    aout[off + 16] = f2bf(o1[rc] * rl);                                                \
    aout[off + 32] = f2bf(o2[rc] * rl);                                                \
    aout[off + 48] = f2bf(o3[rc] * rl);                                                \
} while (0)

    OUT_ROW(0); OUT_ROW(1); OUT_ROW(2); OUT_ROW(3);
}

// ---------------------------------------------------------------------------
extern "C" void kernel_launch(void* const* d_in, const int* in_sizes, int n_in,
                              void* d_out, int out_size, void* d_ws, size_t ws_size,
                              hipStream_t stream)
{
    // identify inputs by element count (robust to ordering)
    const void* x = nullptr; const void* wqkv = nullptr; const void* wout = nullptr;
    for (int i = 0; i < n_in; ++i) {
        if      (in_sizes[i] == 8388608) x    = d_in[i];   // [4,2048,1024]
        else if (in_sizes[i] == 3145728) wqkv = d_in[i];   // [3072,1024]
        else if (in_sizes[i] == 1048576) wout = d_in[i];   // [1024,1024]
    }
    float* out = (float*)d_out;                      // [4,2048,1024] fp32
    unsigned short* ws   = (unsigned short*)d_ws;
    unsigned short* ob16 = (unsigned short*)d_out;   // d_out viewed as bf16 scratch

    // ws (48 MiB + 4 B): qr | kr | aout slots of 8,388,608 bf16 elems each.
    unsigned short* qr     = ws;
    unsigned short* kr     = ws + (size_t)8388608;
    unsigned short* aout   = ws + (size_t)16777216;
    int* flag              = (int*)(ws + (size_t)25165824);
    unsigned short* wqkvbf = aout;   // staged in aout slot; dead before attn writes
    unsigned short* woutbf = qr;     // staged in qr slot AFTER attn (qr then dead)

    // d_out bf16 view: vt [0, 8.4M) | xbf [8.4M, 16.8M); both dead before
    // gemm_out overwrites d_out with fp32 results.
    unsigned short* vt  = ob16;
    unsigned short* xbf = ob16 + (size_t)8388608;

    // 0) input dtype autodetect (bf16 expected; fp32 tolerated)
    detect_f32<<<1, 256, 0, stream>>>((const unsigned short*)x, flag);
    // 1) normalize x and w_qkv to bf16
    norm_bf16<<<4096, 256, 0, stream>>>(x, xbf, 8388608, flag);
    norm_bf16<<<1536, 256, 0, stream>>>(wqkv, wqkvbf, 3145728, flag);
    // 2) fused: qkv GEMM + RoPE(q,k) -> qr/kr [b,h,s,d] (q/8), v -> vt [b,h,d,s]
    gemm_fused<<<dim3(24, 64), 256, 0, stream>>>(xbf, wqkvbf, qr, kr, vt);
    // 3) causal soft-capped flash attention -> aout [tok][1024]
    attn_fwd<<<2048, 256, 0, stream>>>(qr, kr, vt, aout);
    // 4) normalize w_out into the now-dead qr slot
    norm_bf16<<<512, 256, 0, stream>>>(wout, woutbf, 1048576, flag);
    // 5) out_fp32 = aout @ w_out^T  (M=8192, N=1024, K=1024)
    gemm_out<<<dim3(8, 64), 256, 0, stream>>>(aout, woutbf, out);
}